// Round 5
// baseline (286.292 us; speedup 1.0000x reference)
//
#include <hip/hip_runtime.h>
#include <hip/hip_fp16.h>

// MSAAttention: x = e + PE; q,k,v = Linear(x); out = softmax(q k^T) v
// B=8 S=2048 H=512, fp32 in/out. f16 MFMA GEMMs + fp32-math softmax.
//
// Round 5: revert to proven BK=32 / 64-B-row LDS geometry (round-4's BK=64 +
// swizzle tripled bank conflicts); add double-buffered LDS with ONE barrier
// per K-step and the next tile's global_load_lds issued right after the
// barrier, so the barrier's vmcnt drain overlaps a full MFMA stretch.

using half8   = __attribute__((ext_vector_type(8))) _Float16;
using half4v  = __attribute__((ext_vector_type(4))) _Float16;
using floatx4 = __attribute__((ext_vector_type(4))) float;

#define BK 32  // halves per K chunk -> 64 B LDS rows (proven conflict profile)

__device__ __forceinline__ void g2l16(const void* g, void* l) {
  // async global->LDS DMA, 16 B/lane; LDS dest = wave-uniform base + lane*16
  __builtin_amdgcn_global_load_lds((const __attribute__((address_space(1))) void*)g,
                                   (__attribute__((address_space(3))) void*)l, 16, 0, 0);
}

// ---- prep: x16 = f16(embeds + positional encoding) ----
__global__ __launch_bounds__(256) void prep_x_kernel(const float* __restrict__ e,
                                                     _Float16* __restrict__ x16) {
  int t = blockIdx.x * 256 + threadIdx.x;  // 2M threads, 4 elems each
  int idx = t * 4;
  int h = idx & 511;
  int s = (idx >> 9) & 2047;
  float4 ev = *(const float4*)(e + idx);
  const float ks = -9.210340371976184f / 256.0f;  // -ln(10000)/256
  float r[4] = {ev.x, ev.y, ev.z, ev.w};
#pragma unroll
  for (int j = 0; j < 4; j++) {
    int hh = h + j;
    int i = (hh < 256) ? hh : (hh - 256);
    float ang = (float)s * __expf((float)i * ks);
    r[j] += (hh < 256) ? __sinf(ang) : __cosf(ang);
  }
  half4v o = {(_Float16)r[0], (_Float16)r[1], (_Float16)r[2], (_Float16)r[3]};
  *(half4v*)(x16 + idx) = o;
}

// ---- build concatenated f16 weights [1536][512] + fp32 bias [1536] ----
__global__ __launch_bounds__(256) void cvt_w_kernel(const float* __restrict__ wq,
                                                    const float* __restrict__ wk,
                                                    const float* __restrict__ wv,
                                                    const float* __restrict__ bq,
                                                    const float* __restrict__ bk,
                                                    const float* __restrict__ bv,
                                                    _Float16* __restrict__ wcat,
                                                    float* __restrict__ bcat) {
  int i = blockIdx.x * 256 + threadIdx.x;  // 786432
  int m = i & 262143;
  const float* s = (i < 262144) ? wq : (i < 524288) ? wk : wv;
  wcat[i] = (_Float16)s[m];
  if (i < 512) bcat[i] = bq[i];
  else if (i < 1024) bcat[i] = bk[i - 512];
  else if (i < 1536) bcat[i] = bv[i - 1024];
}

// ---- f16 MFMA GEMM: C[m][n] = sum_k A[m][k]*B[n][k] ----
// A [M,K] lda, B [N,K] ldb, k-contiguous. Tile BM x 128, BK=32, 4 waves (2x2),
// wave tile (BM/2) x 64 via 16x16x32 frags. Double-buffered LDS, one barrier
// per K-step, next tile's DMA issued right after the barrier (prefetch flies
// during the MFMA stretch).
// MODE 0: plain store OutT. MODE 1: QKV epilogue (bias; q/k plain, v transposed).
// MODE 2: 1D grid, XCD-aware decode (PV).
template <int BM, typename OutT, int MODE>
__global__ __launch_bounds__(256) void gemm5(const _Float16* __restrict__ A,
                                             const _Float16* __restrict__ B,
                                             const float* __restrict__ bias,
                                             OutT* __restrict__ C,
                                             int lda, int ldb, int ldo, int K,
                                             long long sA, long long sB, long long sC,
                                             _Float16* __restrict__ oq,
                                             _Float16* __restrict__ ok,
                                             _Float16* __restrict__ ov,
                                             int GY) {
  __shared__ _Float16 Ash[2][BM * BK];
  __shared__ _Float16 Bsh[2][128 * BK];
  int bx, by, bz;
  if constexpr (MODE == 2) {
    // the 4 x-blocks of one (y,z) group share i%8 (same XCD) for A-operand L2 reuse
    int i = blockIdx.x;
    int c = i & 7, j = i >> 3;
    bx = j & 3;
    int t = j >> 2;
    int g = c * (gridDim.x >> 5) + t;
    by = g % GY;
    bz = g / GY;
  } else {
    bx = blockIdx.x; by = blockIdx.y; bz = blockIdx.z;
  }
  A += (long long)bz * sA;
  B += (long long)bz * sB;
  C += (long long)bz * sC;
  const int m0 = by * BM, n0 = bx * 128;
  const int tid = threadIdx.x;
  const int lane = tid & 63, wave = tid >> 6;
  constexpr int WM = BM / 2;
  constexpr int MI = WM / 16;
  constexpr int AIt = BM / 64;  // A staging issues per wave (16 rows / issue)
  const int wm = (wave >> 1) * WM, wn = (wave & 1) * 64;
  const int quad = lane >> 4, l16 = lane & 15;
  const int lrow = lane >> 2;       // row within a 16-row staging issue
  const int lcol = (lane & 3) * 8;  // half offset within the 32-half row

  floatx4 acc[MI][4] = {};

  auto issue = [&](int buf, int k0) {
#pragma unroll
    for (int t = 0; t < AIt; t++) {
      int is = wave * AIt + t;
      g2l16(A + (long long)(m0 + is * 16 + lrow) * lda + k0 + lcol, &Ash[buf][is * 16 * BK]);
    }
#pragma unroll
    for (int t = 0; t < 2; t++) {
      int is = wave * 2 + t;
      g2l16(B + (long long)(n0 + is * 16 + lrow) * ldb + k0 + lcol, &Bsh[buf][is * 16 * BK]);
    }
  };

  auto compute = [&](int buf) {
    half8 af[MI], bf[4];
#pragma unroll
    for (int i = 0; i < MI; i++)
      af[i] = *(const half8*)&Ash[buf][(wm + 16 * i + l16) * BK + quad * 8];
#pragma unroll
    for (int i = 0; i < 4; i++)
      bf[i] = *(const half8*)&Bsh[buf][(wn + 16 * i + l16) * BK + quad * 8];
#pragma unroll
    for (int mi = 0; mi < MI; mi++)
#pragma unroll
      for (int ni = 0; ni < 4; ni++)
        acc[mi][ni] = __builtin_amdgcn_mfma_f32_16x16x32_f16(af[mi], bf[ni], acc[mi][ni], 0, 0, 0);
  };

  issue(0, 0);
  for (int k0 = 0; k0 < K; k0 += 2 * BK) {
    __syncthreads();                       // drains tile-k DMA (issued one step ago)
    if (k0 + BK < K) issue(1, k0 + BK);    // prefetch flies during compute(0)
    compute(0);
    __syncthreads();                       // ds_reads of buf0 done; drains buf1 DMA
    if (k0 + 2 * BK < K) issue(0, k0 + 2 * BK);
    compute(1);
  }

  // C/D layout (m89-verified): row(m) = quad*4 + reg, col(n) = lane&15
#pragma unroll
  for (int ni = 0; ni < 4; ni++) {
    const int n = n0 + wn + 16 * ni + l16;
    float bv = 0.0f;
    if constexpr (MODE == 1) bv = bias[n];
#pragma unroll
    for (int mi = 0; mi < MI; mi++) {
      const int mg = m0 + wm + 16 * mi + quad * 4;
#pragma unroll
      for (int rr = 0; rr < 4; rr++) {
        float v = acc[mi][ni][rr] + bv;
        if constexpr (MODE == 1) {
          int m = mg + rr;
          if (n < 512) oq[m * 512 + n] = (_Float16)v;
          else if (n < 1024) ok[m * 512 + (n - 512)] = (_Float16)v;
          else ov[(n - 1024) * 16384 + m] = (_Float16)v;  // V^T
        } else {
          C[(long long)(mg + rr) * ldo + n] = (OutT)v;
        }
      }
    }
  }
}

// ---- softmax over f16 rows of S (2048 wide), fp32 math, f16 in place ----
// One wave per row, shuffle-only reductions. All stores depend on sum (every
// load), so the in-place update is safe.
__global__ __launch_bounds__(256) void softmax_kernel(_Float16* __restrict__ S) {
  const int lane = threadIdx.x & 63;
  const int wave = threadIdx.x >> 6;
  const long long row = (long long)blockIdx.x * 4 + wave;
  _Float16* srow = S + row * 2048;
  float v[32];
  float mx = -3.4e38f;
#pragma unroll
  for (int pass = 0; pass < 4; pass++) {
    half8 f = *(const half8*)(srow + (pass * 64 + lane) * 8);
#pragma unroll
    for (int j = 0; j < 8; j++) {
      float x = (float)f[j];
      v[pass * 8 + j] = x;
      mx = fmaxf(mx, x);
    }
  }
#pragma unroll
  for (int o = 32; o > 0; o >>= 1) mx = fmaxf(mx, __shfl_xor(mx, o));
  float sum = 0.0f;
#pragma unroll
  for (int j = 0; j < 32; j++) {
    v[j] = __expf(v[j] - mx);
    sum += v[j];
  }
#pragma unroll
  for (int o = 32; o > 0; o >>= 1) sum += __shfl_xor(sum, o);
  const float inv = 1.0f / sum;
#pragma unroll
  for (int pass = 0; pass < 4; pass++) {
    half8 o8;
#pragma unroll
    for (int j = 0; j < 8; j++) o8[j] = (_Float16)(v[pass * 8 + j] * inv);
    *(half8*)(srow + (pass * 64 + lane) * 8) = o8;
  }
}

extern "C" void kernel_launch(void* const* d_in, const int* in_sizes, int n_in,
                              void* d_out, int out_size, void* d_ws, size_t ws_size,
                              hipStream_t stream) {
  const float* e  = (const float*)d_in[0];
  const float* Wq = (const float*)d_in[1];
  const float* bq = (const float*)d_in[2];
  const float* Wk = (const float*)d_in[3];
  const float* bk = (const float*)d_in[4];
  const float* Wv = (const float*)d_in[5];
  const float* bv = (const float*)d_in[6];
  float* out = (float*)d_out;
  char* ws = (char*)d_ws;

  const long long MiB = 1024LL * 1024LL;
  // big: S f16 [8][2048][2048] = 64 MiB all at once; small: per-batch 8 MiB
  const bool big = ws_size >= (size_t)(115 * MiB);
  const long long base = big ? 64 * MiB : 16 * MiB;  // x16 needs 16 MiB at head

  _Float16* S    = (_Float16*)ws;
  _Float16* x16  = (_Float16*)ws;  // overlays S head; dead before S written
  _Float16* q16  = (_Float16*)(ws + base);
  _Float16* k16  = (_Float16*)(ws + base + 16 * MiB);
  _Float16* vt   = (_Float16*)(ws + base + 32 * MiB);
  _Float16* wcat = (_Float16*)(ws + base + 48 * MiB);   // 1.5 MiB
  float*    bcat = (float*)(ws + base + 48 * MiB + 1536 * 1024);

  prep_x_kernel<<<8192, 256, 0, stream>>>(e, x16);
  cvt_w_kernel<<<3072, 256, 0, stream>>>(Wq, Wk, Wv, bq, bk, bv, wcat, bcat);

  // fused QKV: M=16384 N=1536 K=512; epilogue routes q/k plain, v transposed
  gemm5<128, _Float16, 1><<<dim3(12, 128, 1), 256, 0, stream>>>(
      x16, wcat, bcat, (_Float16*)nullptr, 512, 512, 0, 512, 0, 0, 0, q16, k16, vt, 0);

  if (big) {
    // S = q k^T batched: M=N=2048 K=512, f16 out
    gemm5<128, _Float16, 0><<<dim3(16, 16, 8), 256, 0, stream>>>(
        q16, k16, nullptr, S, 512, 512, 2048, 512,
        1048576LL, 1048576LL, 4194304LL, nullptr, nullptr, nullptr, 0);
    softmax_kernel<<<4096, 256, 0, stream>>>(S);
    // out = P v: BM=64, 1D grid 1024 with XCD decode; GY = 2048/64 = 32
    gemm5<64, float, 2><<<dim3(1024, 1, 1), 256, 0, stream>>>(
        S, vt, nullptr, out, 2048, 16384, 512, 2048,
        4194304LL, 2048LL, 1048576LL, nullptr, nullptr, nullptr, 32);
  } else {
    for (int b = 0; b < 8; b++) {
      gemm5<128, _Float16, 0><<<dim3(16, 16, 1), 256, 0, stream>>>(
          q16 + (long long)b * 1048576, k16 + (long long)b * 1048576, nullptr, S,
          512, 512, 2048, 512, 0, 0, 0, nullptr, nullptr, nullptr, 0);
      softmax_kernel<<<512, 256, 0, stream>>>(S);
      gemm5<64, float, 2><<<dim3(128, 1, 1), 256, 0, stream>>>(
          S, vt + (long long)b * 2048, nullptr, out + (long long)b * 1048576,
          2048, 16384, 512, 2048, 0, 0, 0, nullptr, nullptr, nullptr, 32);
    }
  }
}

// Round 6
// 272.062 us; speedup vs baseline: 1.0523x; 1.0523x over previous
//
#include <hip/hip_runtime.h>
#include <hip/hip_fp16.h>

// MSAAttention: x = e + PE; q,k,v = Linear(x); out = softmax(q k^T) v
// B=8 S=2048 H=512, fp32 in/out. f16 MFMA GEMMs + fp32-math softmax.
//
// Round 6: XCD-aware block decode on ALL GEMMs (tile-sharing blocks pinned to
// one XCD via id%8 so DMA latency is L2-class, which the double-buffer's
// compute stretch can actually hide). BK=32 / 64-B LDS rows (proven), dbuf
// with one barrier per K-step. prep+cvt merged into one launch.

using half8   = __attribute__((ext_vector_type(8))) _Float16;
using half4v  = __attribute__((ext_vector_type(4))) _Float16;
using floatx4 = __attribute__((ext_vector_type(4))) float;

#define BK 32  // halves per K chunk -> 64 B LDS rows

__device__ __forceinline__ void g2l16(const void* g, void* l) {
  // async global->LDS DMA, 16 B/lane; LDS dest = wave-uniform base + lane*16
  __builtin_amdgcn_global_load_lds((const __attribute__((address_space(1))) void*)g,
                                   (__attribute__((address_space(3))) void*)l, 16, 0, 0);
}

// ---- prep (blocks 0..8191): x16 = f16(embeds + PE)
// ---- cvt  (blocks 8192..11263): wcat f16 [1536][512] + bcat fp32 [1536]
__global__ __launch_bounds__(256) void prep_cvt_kernel(const float* __restrict__ e,
                                                       _Float16* __restrict__ x16,
                                                       const float* __restrict__ wq,
                                                       const float* __restrict__ wk,
                                                       const float* __restrict__ wv,
                                                       const float* __restrict__ bq,
                                                       const float* __restrict__ bk,
                                                       const float* __restrict__ bv,
                                                       _Float16* __restrict__ wcat,
                                                       float* __restrict__ bcat) {
  if (blockIdx.x < 8192) {
    int t = blockIdx.x * 256 + threadIdx.x;  // 2M threads, 4 elems each
    int idx = t * 4;
    int h = idx & 511;
    int s = (idx >> 9) & 2047;
    float4 ev = *(const float4*)(e + idx);
    const float ks = -9.210340371976184f / 256.0f;  // -ln(10000)/256
    float r[4] = {ev.x, ev.y, ev.z, ev.w};
#pragma unroll
    for (int j = 0; j < 4; j++) {
      int hh = h + j;
      int i = (hh < 256) ? hh : (hh - 256);
      float ang = (float)s * __expf((float)i * ks);
      r[j] += (hh < 256) ? __sinf(ang) : __cosf(ang);
    }
    half4v o = {(_Float16)r[0], (_Float16)r[1], (_Float16)r[2], (_Float16)r[3]};
    *(half4v*)(x16 + idx) = o;
  } else {
    int i = (blockIdx.x - 8192) * 256 + threadIdx.x;  // 786432
    int m = i & 262143;
    const float* s = (i < 262144) ? wq : (i < 524288) ? wk : wv;
    wcat[i] = (_Float16)s[m];
    if (i < 512) bcat[i] = bq[i];
    else if (i < 1024) bcat[i] = bk[i - 512];
    else if (i < 1536) bcat[i] = bv[i - 1024];
  }
}

// ---- f16 MFMA GEMM: C[m][n] = sum_k A[m][k]*B[n][k] ----
// A [M,K] lda, B [N,K] ldb, k-contiguous. Tile BM x 128, BK=32, 4 waves (2x2),
// wave tile (BM/2) x 64 via 16x16x32 frags. Double-buffered LDS, one barrier
// per K-step, next tile's DMA issued right after the barrier.
// MODE 0: plain 3D grid, plain store.
// MODE 1: QKV — 1D grid 1536, XCD decode (by-groups of 16 per XCD, bx = j%12),
//         epilogue bias + route q/k plain, v transposed.
// MODE 2: 1D grid, XCD decode bz = id&7 (batch->XCD), bx = j & (2^LBX - 1).
template <int BM, typename OutT, int MODE, int LBX>
__global__ __launch_bounds__(256) void gemm6(const _Float16* __restrict__ A,
                                             const _Float16* __restrict__ B,
                                             const float* __restrict__ bias,
                                             OutT* __restrict__ C,
                                             int lda, int ldb, int ldo, int K,
                                             long long sA, long long sB, long long sC,
                                             _Float16* __restrict__ oq,
                                             _Float16* __restrict__ ok,
                                             _Float16* __restrict__ ov) {
  __shared__ _Float16 Ash[2][BM * BK];
  __shared__ _Float16 Bsh[2][128 * BK];
  int bx, by, bz;
  if constexpr (MODE == 1) {
    unsigned i = blockIdx.x;           // 1536 blocks
    unsigned c = i & 7, j = i >> 3;    // j in [0,192)
    by = c * 16 + j / 12;              // XCD c owns by-range [16c,16c+16)
    bx = j % 12;
    bz = 0;
  } else if constexpr (MODE == 2) {
    unsigned i = blockIdx.x;
    unsigned c = i & 7, j = i >> 3;
    bz = c;                            // batch -> XCD: operands L2-resident
    bx = j & ((1u << LBX) - 1);
    by = j >> LBX;
  } else {
    bx = blockIdx.x; by = blockIdx.y; bz = blockIdx.z;
  }
  A += (long long)bz * sA;
  B += (long long)bz * sB;
  C += (long long)bz * sC;
  const int m0 = by * BM, n0 = bx * 128;
  const int tid = threadIdx.x;
  const int lane = tid & 63, wave = tid >> 6;
  constexpr int WM = BM / 2;
  constexpr int MI = WM / 16;
  constexpr int AIt = BM / 64;  // A staging issues per wave (16 rows / issue)
  const int wm = (wave >> 1) * WM, wn = (wave & 1) * 64;
  const int quad = lane >> 4, l16 = lane & 15;
  const int lrow = lane >> 2;       // row within a 16-row staging issue
  const int lcol = (lane & 3) * 8;  // half offset within the 32-half row

  floatx4 acc[MI][4] = {};

  auto issue = [&](int buf, int k0) {
#pragma unroll
    for (int t = 0; t < AIt; t++) {
      int is = wave * AIt + t;
      g2l16(A + (long long)(m0 + is * 16 + lrow) * lda + k0 + lcol, &Ash[buf][is * 16 * BK]);
    }
#pragma unroll
    for (int t = 0; t < 2; t++) {
      int is = wave * 2 + t;
      g2l16(B + (long long)(n0 + is * 16 + lrow) * ldb + k0 + lcol, &Bsh[buf][is * 16 * BK]);
    }
  };

  auto compute = [&](int buf) {
    half8 af[MI], bf[4];
#pragma unroll
    for (int i = 0; i < MI; i++)
      af[i] = *(const half8*)&Ash[buf][(wm + 16 * i + l16) * BK + quad * 8];
#pragma unroll
    for (int i = 0; i < 4; i++)
      bf[i] = *(const half8*)&Bsh[buf][(wn + 16 * i + l16) * BK + quad * 8];
#pragma unroll
    for (int mi = 0; mi < MI; mi++)
#pragma unroll
      for (int ni = 0; ni < 4; ni++)
        acc[mi][ni] = __builtin_amdgcn_mfma_f32_16x16x32_f16(af[mi], bf[ni], acc[mi][ni], 0, 0, 0);
  };

  issue(0, 0);
  for (int k0 = 0; k0 < K; k0 += 2 * BK) {
    __syncthreads();                       // drains tile-k DMA (issued one step ago)
    if (k0 + BK < K) issue(1, k0 + BK);    // prefetch flies during compute(0)
    compute(0);
    __syncthreads();                       // ds_reads of buf0 done; drains buf1 DMA
    if (k0 + 2 * BK < K) issue(0, k0 + 2 * BK);
    compute(1);
  }

  // C/D layout (m89-verified): row(m) = quad*4 + reg, col(n) = lane&15
#pragma unroll
  for (int ni = 0; ni < 4; ni++) {
    const int n = n0 + wn + 16 * ni + l16;
    float bv = 0.0f;
    if constexpr (MODE == 1) bv = bias[n];
#pragma unroll
    for (int mi = 0; mi < MI; mi++) {
      const int mg = m0 + wm + 16 * mi + quad * 4;
#pragma unroll
      for (int rr = 0; rr < 4; rr++) {
        float v = acc[mi][ni][rr] + bv;
        if constexpr (MODE == 1) {
          int m = mg + rr;
          if (n < 512) oq[m * 512 + n] = (_Float16)v;
          else if (n < 1024) ok[m * 512 + (n - 512)] = (_Float16)v;
          else ov[(n - 1024) * 16384 + m] = (_Float16)v;  // V^T
        } else {
          C[(long long)(mg + rr) * ldo + n] = (OutT)v;
        }
      }
    }
  }
}

// ---- softmax over f16 rows of S (2048 wide), fp32 math, f16 in place ----
// One wave per row, shuffle-only reductions. All stores depend on sum (every
// load), so the in-place update is safe.
__global__ __launch_bounds__(256) void softmax_kernel(_Float16* __restrict__ S) {
  const int lane = threadIdx.x & 63;
  const int wave = threadIdx.x >> 6;
  const long long row = (long long)blockIdx.x * 4 + wave;
  _Float16* srow = S + row * 2048;
  float v[32];
  float mx = -3.4e38f;
#pragma unroll
  for (int pass = 0; pass < 4; pass++) {
    half8 f = *(const half8*)(srow + (pass * 64 + lane) * 8);
#pragma unroll
    for (int j = 0; j < 8; j++) {
      float x = (float)f[j];
      v[pass * 8 + j] = x;
      mx = fmaxf(mx, x);
    }
  }
#pragma unroll
  for (int o = 32; o > 0; o >>= 1) mx = fmaxf(mx, __shfl_xor(mx, o));
  float sum = 0.0f;
#pragma unroll
  for (int j = 0; j < 32; j++) {
    v[j] = __expf(v[j] - mx);
    sum += v[j];
  }
#pragma unroll
  for (int o = 32; o > 0; o >>= 1) sum += __shfl_xor(sum, o);
  const float inv = 1.0f / sum;
#pragma unroll
  for (int pass = 0; pass < 4; pass++) {
    half8 o8;
#pragma unroll
    for (int j = 0; j < 8; j++) o8[j] = (_Float16)(v[pass * 8 + j] * inv);
    *(half8*)(srow + (pass * 64 + lane) * 8) = o8;
  }
}

extern "C" void kernel_launch(void* const* d_in, const int* in_sizes, int n_in,
                              void* d_out, int out_size, void* d_ws, size_t ws_size,
                              hipStream_t stream) {
  const float* e  = (const float*)d_in[0];
  const float* Wq = (const float*)d_in[1];
  const float* bq = (const float*)d_in[2];
  const float* Wk = (const float*)d_in[3];
  const float* bk = (const float*)d_in[4];
  const float* Wv = (const float*)d_in[5];
  const float* bv = (const float*)d_in[6];
  float* out = (float*)d_out;
  char* ws = (char*)d_ws;

  const long long MiB = 1024LL * 1024LL;
  // big: S f16 [8][2048][2048] = 64 MiB at once; small: per-batch 8 MiB
  const bool big = ws_size >= (size_t)(115 * MiB);
  const long long base = big ? 64 * MiB : 16 * MiB;  // x16 needs 16 MiB at head

  _Float16* S    = (_Float16*)ws;
  _Float16* x16  = (_Float16*)ws;  // overlays S head; dead before S written
  _Float16* q16  = (_Float16*)(ws + base);
  _Float16* k16  = (_Float16*)(ws + base + 16 * MiB);
  _Float16* vt   = (_Float16*)(ws + base + 32 * MiB);
  _Float16* wcat = (_Float16*)(ws + base + 48 * MiB);   // 1.5 MiB
  float*    bcat = (float*)(ws + base + 48 * MiB + 1536 * 1024);

  prep_cvt_kernel<<<11264, 256, 0, stream>>>(e, x16, Wq, Wk, Wv, bq, bk, bv, wcat, bcat);

  // fused QKV: M=16384 N=1536 K=512; XCD-decoded 1D grid; q/k plain, v transposed
  gemm6<128, _Float16, 1, 0><<<1536, 256, 0, stream>>>(
      x16, wcat, bcat, (_Float16*)nullptr, 512, 512, 0, 512, 0, 0, 0, q16, k16, vt);

  if (big) {
    // S = q k^T batched: M=N=2048 K=512 f16 out; batch->XCD, bx = j&15
    gemm6<128, _Float16, 2, 4><<<2048, 256, 0, stream>>>(
        q16, k16, nullptr, S, 512, 512, 2048, 512,
        1048576LL, 1048576LL, 4194304LL, nullptr, nullptr, nullptr);
    softmax_kernel<<<4096, 256, 0, stream>>>(S);
    // out = P v: BM=64; batch->XCD, bx = j&3
    gemm6<64, float, 2, 2><<<1024, 256, 0, stream>>>(
        S, vt, nullptr, out, 2048, 16384, 512, 2048,
        4194304LL, 2048LL, 1048576LL, nullptr, nullptr, nullptr);
  } else {
    for (int b = 0; b < 8; b++) {
      gemm6<128, _Float16, 0, 0><<<dim3(16, 16, 1), 256, 0, stream>>>(
          q16 + (long long)b * 1048576, k16 + (long long)b * 1048576, nullptr, S,
          512, 512, 2048, 512, 0, 0, 0, nullptr, nullptr, nullptr);
      softmax_kernel<<<512, 256, 0, stream>>>(S);
      gemm6<64, float, 0, 0><<<dim3(4, 32, 1), 256, 0, stream>>>(
          S, vt + (long long)b * 2048, nullptr, out + (long long)b * 1048576,
          2048, 16384, 512, 2048, 0, 0, 0, nullptr, nullptr, nullptr);
    }
  }
}